// Round 15
// baseline (164.798 us; speedup 1.0000x reference)
//
#include <hip/hip_runtime.h>
#include <cstddef>

typedef unsigned short u16;
typedef __attribute__((ext_vector_type(4))) float floatx4;
typedef __attribute__((ext_vector_type(8))) short short8;
typedef __attribute__((ext_vector_type(4))) unsigned int uintx4;

#define TT 2048
#define DD 1024
#define NH 16
#define ATT_SCALE (1.0f / 32.0f)

__device__ __forceinline__ u16 f2bf(float f) {
  unsigned u = __builtin_bit_cast(unsigned, f);
  u += 0x7fffu + ((u >> 16) & 1u);  // RNE
  return (u16)(u >> 16);
}

// pack two f32 -> (bf16,bf16) in one u32, a in low half (RNE)
__device__ __forceinline__ unsigned pack2(float a, float b) {
#if __has_builtin(__builtin_amdgcn_cvt_pk_bf16_f32)
  auto t = __builtin_amdgcn_cvt_pk_bf16_f32(a, b);
  return __builtin_bit_cast(unsigned, t);
#else
  unsigned ua = __builtin_bit_cast(unsigned, a);
  ua += 0x7fffu + ((ua >> 16) & 1u);
  unsigned ub = __builtin_bit_cast(unsigned, b);
  ub += 0x7fffu + ((ub >> 16) & 1u);
  return (ua >> 16) | (ub & 0xffff0000u);
#endif
}

// async global->LDS, 16B per lane (LDS dest wave-uniform base + lane*16)
__device__ __forceinline__ void g2l16(const u16* g, u16* l) {
#if __has_builtin(__builtin_amdgcn_global_load_lds)
  __builtin_amdgcn_global_load_lds(
      (const __attribute__((address_space(1))) unsigned int*)g,
      (__attribute__((address_space(3))) unsigned int*)l, 16, 0, 0);
#else
  *(int4*)l = *(const int4*)g;
#endif
}

// scale bf16x8 by 1/32 (exact: exponent shift)
__device__ __forceinline__ short8 scale_q(short8 q) {
  short8 r;
#pragma unroll
  for (int i = 0; i < 8; ++i) {
    float f = __builtin_bit_cast(float, ((unsigned)(u16)q[i]) << 16) * ATT_SCALE;
    r[i] = (short)f2bf(f);
  }
  return r;
}

// one kernel for all three fp32->bf16 conversions (outputs contiguous in ws)
__global__ __launch_bounds__(256) void cvt3_kernel(const float* __restrict__ a,
                                                   const float* __restrict__ b,
                                                   const float* __restrict__ c,
                                                   u16* __restrict__ out,
                                                   int na, int nb, int nc) {
  int i = blockIdx.x * 256 + threadIdx.x;
  const float* src;
  int j;
  if (i < na) { src = a; j = i; }
  else if (i < na + nb) { src = b; j = i - na; }
  else if (i < na + nb + nc) { src = c; j = i - na - nb; }
  else return;
  float4 v = ((const float4*)src)[j];
  ((ushort4*)out)[i] = make_ushort4(f2bf(v.x), f2bf(v.y), f2bf(v.z), f2bf(v.w));
}

// C[m,n] = sum_k A[m,k]*Bm[n,k]. 128xBN tile, double-buffered BK=32 chunks
// with plain __syncthreads. SESSION-MEASURED OPTIMUM for this template
// (R6/R7/R9/R10 triangulation; counted-vmcnt asm and 256^2 tiles both
// regress). Epilogue via 32KB LDS scratch -> coalesced 16B stores.
// MODE 2 (qkv-fused): cols<2048 -> bf16 qk buffer (width 2048);
//                     cols>=2048 -> V written TRANSPOSED to vt.
// R15: MODE 2 uses a 1D grid (768 blocks) with T1 L2-CHUNKED decode --
// each XCD's 96 blocks (id%8 const under round-robin dispatch) form a
// compact 8m x 12n rectangle: per-XCD panel set 20 x 256KB = 5MB (was
// x-major: 4 A-panels + ALL 24 B-panels = 7MB > 4MB L2 -> B staging
// missed to L3/HBM; R8 profile: qkv FETCH 29MB vs 14MB unique).
template <int MODE, int BN>
__global__ __launch_bounds__(256) void gemm_ep(const u16* __restrict__ A,
                                               const u16* __restrict__ Bm,
                                               void* __restrict__ C,
                                               u16* __restrict__ vt,
                                               int M, int N, int K) {
  constexpr int NT = BN / 32;
  __shared__ __attribute__((aligned(16))) unsigned char shmem[32768];
  u16* As = (u16*)shmem;                 // [2][128*32]
  u16* Bs = As + 2 * 128 * 32;           // [2][BN*32]

  const int tid = threadIdx.x;
  const int lane = tid & 63;
  const int wave = tid >> 6;
  const int quad = lane >> 4;
  const int l16 = lane & 15;
  const int wm = (wave >> 1) * 64;
  const int wn = (wave & 1) * (BN / 2);

  int bx, by;
  if constexpr (MODE == 2) {
    // T1 chunked decode: grid = 768 x 1, XCD c gets rectangle
    // m in [ (c&3)*8, +8 ), n in [ (c>>2)*12, +12 )
    const int L = blockIdx.x;
    const int c = L & 7;
    const int j = L >> 3;          // 0..95
    bx = (c & 3) * 8 + j / 12;     // 0..31
    by = (c >> 2) * 12 + j % 12;   // 0..23
  } else {
    bx = blockIdx.x;
    by = blockIdx.y;
  }
  const int m0 = bx * 128;
  const int n0 = by * BN;

  const int srow = tid >> 2;        // 0..63 (row within a 64-row staging half)
  const int scol = (tid & 3) * 8;   // 8-u16 chunk within the 32-wide row
  const int sl = tid * 8;           // linear LDS dest (u16), lane*16B per wave

  floatx4 acc[4][NT] = {};

  auto stage = [&](int b, int k0) {
    g2l16(&A[(size_t)(m0 + srow) * K + k0 + scol], &As[b * 4096 + sl]);
    g2l16(&A[(size_t)(m0 + 64 + srow) * K + k0 + scol], &As[b * 4096 + 2048 + sl]);
    g2l16(&Bm[(size_t)(n0 + srow) * K + k0 + scol], &Bs[b * (BN * 32) + sl]);
    if (BN == 128)
      g2l16(&Bm[(size_t)(n0 + 64 + srow) * K + k0 + scol], &Bs[b * 4096 + 2048 + sl]);
  };
  auto compute = [&](int b) {
    short8 af[4];
#pragma unroll
    for (int mt = 0; mt < 4; ++mt)
      af[mt] = *(const short8*)&As[b * 4096 + (wm + mt * 16 + l16) * 32 + quad * 8];
#pragma unroll
    for (int nt = 0; nt < NT; ++nt) {
      short8 bf = *(const short8*)&Bs[b * (BN * 32) + (wn + nt * 16 + l16) * 32 + quad * 8];
#pragma unroll
      for (int mt = 0; mt < 4; ++mt)
        acc[mt][nt] = __builtin_amdgcn_mfma_f32_16x16x32_bf16(af[mt], bf, acc[mt][nt], 0, 0, 0);
    }
  };

  stage(0, 0);
  for (int k0 = 0; k0 < K; k0 += 64) {
    __syncthreads();                       // drains stage(buf0, chunk k0)
    if (k0 + 32 < K) stage(1, k0 + 32);    // flies under compute(0)
    compute(0);
    __syncthreads();                       // drains stage(buf1); compute(0) done
    if (k0 + 64 < K) stage(0, k0 + 64);    // flies under compute(1)
    compute(1);
  }

  __syncthreads();  // all staging reads done -> shmem becomes epilogue scratch

  if (MODE == 2 && n0 >= 2048) {
    // V region, transposed: scratch [n_local][t_local] u16 (128x128 = 32KB),
    // t XOR-swizzled by (n&7)<<3 (bits 3..5; preserves 4-u16 write alignment).
    u16* scr = (u16*)shmem;
    const int bidx = m0 >> 11;
    const int tb = m0 & 2047;
#pragma unroll
    for (int mt = 0; mt < 4; ++mt)
#pragma unroll
      for (int nt = 0; nt < NT; ++nt) {
        int nl = wn + nt * 16 + l16;
        int tl = wm + mt * 16 + quad * 4;
        int sz = (nl & 7) << 3;
        *(unsigned*)&scr[nl * 128 + (tl ^ sz)] = pack2(acc[mt][nt][0], acc[mt][nt][1]);
        *(unsigned*)&scr[nl * 128 + ((tl + 2) ^ sz)] = pack2(acc[mt][nt][2], acc[mt][nt][3]);
      }
    __syncthreads();
    // stream out: 8 passes x 16 n-rows x 256B contiguous along t
#pragma unroll
    for (int ps = 0; ps < 8; ++ps) {
      int nl = ps * 16 + (tid >> 4);
      int ck = (tid & 15) * 8;
      int sz = (nl & 7) << 3;
      int4 v = *(const int4*)&scr[nl * 128 + (ck ^ sz)];
      size_t vrow = (size_t)(bidx * 1024 + n0 + nl - 2048);
      *(int4*)&vt[vrow * TT + tb + ck] = v;
    }
  } else if (MODE >= 1) {
    // bf16 [m][BN] scratch, col XOR-swizzled by quad bits to de-alias banks
    const int cw = (MODE == 2) ? 2048 : N;
    constexpr int SH = (BN == 128) ? 5 : 4;
    u16* scr = (u16*)shmem;
#pragma unroll
    for (int mt = 0; mt < 4; ++mt)
#pragma unroll
      for (int nt = 0; nt < NT; ++nt)
#pragma unroll
        for (int r = 0; r < 4; ++r) {
          int ml = wm + mt * 16 + quad * 4 + r;
          int nl = wn + nt * 16 + l16;
          scr[ml * BN + (nl ^ (((ml >> 2) & 3) << SH))] = f2bf(acc[mt][nt][r]);
        }
    __syncthreads();
    constexpr int RPP = 2048 / BN;          // rows per pass (16 or 32)
    constexpr int CPT = BN / 8;             // col-chunks per row
#pragma unroll
    for (int ps = 0; ps < 128 / RPP; ++ps) {
      int ml = ps * RPP + tid / CPT;
      int ck = (tid % CPT) * 8;
      int sz = ((ml >> 2) & 3) << SH;
      int4 v = *(const int4*)&scr[ml * BN + (ck ^ sz)];
      *(int4*)&((u16*)C)[(size_t)(m0 + ml) * cw + n0 + ck] = v;
    }
  } else {
    // fp32 [m][64] scratch (32KB), col XOR-swizzled by quad bits
    float* scrf = (float*)shmem;
#pragma unroll
    for (int mt = 0; mt < 4; ++mt)
#pragma unroll
      for (int nt = 0; nt < NT; ++nt)
#pragma unroll
        for (int r = 0; r < 4; ++r) {
          int ml = wm + mt * 16 + quad * 4 + r;
          int nl = wn + nt * 16 + l16;
          scrf[ml * 64 + (nl ^ (((ml >> 2) & 3) << 4))] = acc[mt][nt][r];
        }
    __syncthreads();
#pragma unroll
    for (int ps = 0; ps < 8; ++ps) {
      int ml = ps * 16 + (tid >> 4);
      int ck = (tid & 15) * 4;
      int sz = ((ml >> 2) & 3) << 4;
      float4 v = *(const float4*)&scrf[ml * 64 + (ck ^ sz)];
      *(float4*)&((float*)C)[(size_t)(m0 + ml) * N + n0 + ck] = v;
    }
  }
}

// out-GEMM specialization: 128x64 tile, BK=64 chunks double-buffered.
// R3-verified T2 both-sides swizzle + R6 dbuf skeleton. R14: WIN (-2.6us).
// LDS 48KB -> 3 blocks/CU allowed (grid gives 2). fp32 LDS-scratch epilogue.
__global__ __launch_bounds__(256) void gemm_out64(const u16* __restrict__ A,
                                                  const u16* __restrict__ Bm,
                                                  float* __restrict__ C) {
  constexpr int K = 1024;
  constexpr int N = 1024;
  __shared__ __attribute__((aligned(16))) unsigned char shmem[49152];
  u16* As = (u16*)shmem;                 // [2][128*64] = 32 KB
  u16* Bs = As + 2 * 128 * 64;           // [2][64*64]  = 16 KB

  const int tid = threadIdx.x;
  const int lane = tid & 63;
  const int wave = tid >> 6;
  const int quad = lane >> 4;
  const int l16 = lane & 15;
  const int wm = (wave >> 1) * 64;
  const int wn = (wave & 1) * 32;
  const int m0 = blockIdx.x * 128;
  const int n0 = blockIdx.y * 64;

  // staging: per gload op, 256 thr cover 32 rows x 64 cols (8-u16 chunks)
  const int srow = tid >> 3;                        // 0..31
  const int scol = ((tid & 7) ^ (srow & 7)) * 8;    // pre-swizzled source col
  const int sdst = tid * 8;                         // linear LDS (u16)
  const int sw8 = l16 & 7;                          // read-side swizzle

  floatx4 acc[4][2] = {};

  auto stage = [&](int b, int k0) {
#pragma unroll
    for (int o = 0; o < 4; ++o)
      g2l16(&A[(size_t)(m0 + o * 32 + srow) * K + k0 + scol],
            &As[b * 8192 + o * 2048 + sdst]);
#pragma unroll
    for (int o = 0; o < 2; ++o)
      g2l16(&Bm[(size_t)(n0 + o * 32 + srow) * K + k0 + scol],
            &Bs[b * 4096 + o * 2048 + sdst]);
  };
  auto compute = [&](int b) {
#pragma unroll
    for (int kk = 0; kk < 2; ++kk) {
      short8 af[4];
#pragma unroll
      for (int mt = 0; mt < 4; ++mt)
        af[mt] = *(const short8*)&As[b * 8192 + (wm + mt * 16 + l16) * 64 +
                                     (((kk << 2) | quad) ^ sw8) * 8];
#pragma unroll
      for (int nt = 0; nt < 2; ++nt) {
        short8 bf = *(const short8*)&Bs[b * 4096 + (wn + nt * 16 + l16) * 64 +
                                        (((kk << 2) | quad) ^ sw8) * 8];
#pragma unroll
        for (int mt = 0; mt < 4; ++mt)
          acc[mt][nt] = __builtin_amdgcn_mfma_f32_16x16x32_bf16(af[mt], bf, acc[mt][nt], 0, 0, 0);
      }
    }
  };

  stage(0, 0);
  for (int k0 = 0; k0 < K; k0 += 128) {
    __syncthreads();                        // stage(buf0, k0) landed
    stage(1, k0 + 64);                      // k0+64 <= 960 < K always
    compute(0);
    __syncthreads();                        // stage(buf1) landed; buf0 free
    if (k0 + 128 < K) stage(0, k0 + 128);
    compute(1);
  }

  __syncthreads();  // shmem becomes epilogue scratch
  // fp32 [m][64] scratch (32KB), col XOR-swizzled by quad bits
  float* scrf = (float*)shmem;
#pragma unroll
  for (int mt = 0; mt < 4; ++mt)
#pragma unroll
    for (int nt = 0; nt < 2; ++nt)
#pragma unroll
      for (int r = 0; r < 4; ++r) {
        int ml = wm + mt * 16 + quad * 4 + r;
        int nl = wn + nt * 16 + l16;
        scrf[ml * 64 + (nl ^ (((ml >> 2) & 3) << 4))] = acc[mt][nt][r];
      }
  __syncthreads();
#pragma unroll
  for (int ps = 0; ps < 8; ++ps) {
    int ml = ps * 16 + (tid >> 4);
    int ck = (tid & 15) * 4;
    int sz = ((ml >> 2) & 3) << 4;
    float4 v = *(const float4*)&scrf[ml * 64 + (ck ^ sz)];
    *(float4*)&C[(size_t)(m0 + ml) * N + n0 + ck] = v;
  }
}

// exp + causal-mask + pack to bf16 pairs, per nt-block. DIAG: apply mask.
template <bool DIAG>
__device__ __forceinline__ void exp_pack(const floatx4* s, int kt0, int quad,
                                         int qr, float& ps, unsigned W[4][2]) {
#pragma unroll
  for (int nt = 0; nt < 4; ++nt) {
    float e[4];
#pragma unroll
    for (int r = 0; r < 4; ++r) {
      float v = __expf(s[nt][r]);
      if (DIAG) {
        int kk = kt0 + nt * 16 + quad * 4 + r;
        v = (kk <= qr) ? v : 0.f;
      }
      ps += v;
      e[r] = v;
    }
    W[nt][0] = pack2(e[0], e[1]);
    W[nt][1] = pack2(e[2], e[3]);
  }
}

// Build the PV A-fragment in-register from swapped-QK^T output.
// Lane (quad,l16) holds P[q=l16][k=16nt+4quad+r] (packed in W[nt][c]).
// A-frag needs P[q=l16][k=quad*8+j]: word j2 of pa0 pulls W[quad>>1][j2&1]
// from src lane ((quad&1)*32 + (j2>>1)*16 + l16); pa1 uses W[2|3].
__device__ __forceinline__ void pfrag(const unsigned W[4][2], int bpA, int bpB,
                                      int quad, short8& pa0, short8& pa1) {
  uintx4 a, b;
#pragma unroll
  for (int c = 0; c < 2; ++c) {
    unsigned x0 = (unsigned)__builtin_amdgcn_ds_bpermute(bpA, (int)W[0][c]);
    unsigned x1 = (unsigned)__builtin_amdgcn_ds_bpermute(bpA, (int)W[1][c]);
    unsigned y0 = (unsigned)__builtin_amdgcn_ds_bpermute(bpB, (int)W[0][c]);
    unsigned y1 = (unsigned)__builtin_amdgcn_ds_bpermute(bpB, (int)W[1][c]);
    a[c]     = (quad < 2) ? x0 : x1;
    a[2 + c] = (quad < 2) ? y0 : y1;
    unsigned u0 = (unsigned)__builtin_amdgcn_ds_bpermute(bpA, (int)W[2][c]);
    unsigned u1 = (unsigned)__builtin_amdgcn_ds_bpermute(bpA, (int)W[3][c]);
    unsigned t0 = (unsigned)__builtin_amdgcn_ds_bpermute(bpB, (int)W[2][c]);
    unsigned t1 = (unsigned)__builtin_amdgcn_ds_bpermute(bpB, (int)W[3][c]);
    b[c]     = (quad < 2) ? u0 : u1;
    b[2 + c] = (quad < 2) ? t0 : t1;
  }
  pa0 = __builtin_bit_cast(short8, a);
  pa1 = __builtin_bit_cast(short8, b);
}

// Paired flash attention, 512 threads = 4 q-slices x 2 key-parities.
// Swapped QK^T (mfma(K,Q) -> S^T with q lane-local), softmax + P->bf16
// fully in-register (cvt_pk + ds_bpermute), no Ps LDS round-trip.
// Ks/Vs stride 64 + XOR swizzle col^((row&7)<<3) -> conflict-free ds_read_b128.
// 32 KB LDS. Unnormalized-exp key-associative parity accumulation.
// Pairing (qtA=p, qtB=31-p) keeps per-block work uniform AND lets A reuse B's
// staged K/V tiles -- all waves stay busy.
// T1 XCD CO-LOCATION (R12: FETCH 67->12.9 MB, dur -10%): 1D bh-major grid
// (id%8 == bh%8) pins same-head blocks to one XCD L2 (2MB K/V <= 4MB L2).
// SESSION LEDGER (structure optimum):
//   R2: un-paired 1-tile blocks            -> 1.8x WORSE (imbalance + reg choke)
//   R5: 32-row split tiles                 -> 1.4x WORSE (wave idling)
//   R10: merged A/B sharing K/V LDS reads  -> 3x WORSE (VGPR spill, 225MB scratch)
//   R4: T14 async-STAGE split              -> 53.2 -> 44.5 us (KEPT)
//   R12: T1 bh-major grid                  -> 48.2 -> 43.4 us (KEPT)
__global__ __launch_bounds__(512, 4) void attn_flash8(const u16* __restrict__ qk,
                                                      const u16* __restrict__ vt,
                                                      u16* __restrict__ z) {
  __shared__ u16 Ks[2][64 * 64];   // per key-parity tile: Ks[p][key][d], swizzled
  __shared__ u16 Vs[2][64 * 64];   // Vs[p][d][key], swizzled

  const int tid = threadIdx.x;
  const int lane = tid & 63;
  const int wave = tid >> 6;   // 0..7
  const int qs = wave & 3;     // q-slice (16 rows)
  const int par = wave >> 2;   // key parity
  const int quad = lane >> 4;
  const int l16 = lane & 15;

  // T1: bh-major 1D grid (id%8 == bh%8 -> same-head blocks share an XCD L2)
  const int p = blockIdx.x >> 5;      // 0..15
  const int bh = blockIdx.x & 31;     // 0..31
  const int qtA = p, qtB = 31 - p;
  const int b = bh >> 4, h = bh & 15;

  const size_t bbase = (size_t)b * TT * 2048;
  const u16* qg = qk + bbase + h * 64;
  const u16* kg = qk + bbase + 1024 + h * 64;
  const u16* vtg = vt + (size_t)bh * 64 * TT;

  short8 qfA[2], qfB[2];
  {
    const size_t ra = (size_t)(qtA * 64 + qs * 16 + l16) * 2048;
    const size_t rb = (size_t)(qtB * 64 + qs * 16 + l16) * 2048;
    qfA[0] = scale_q(*(const short8*)&qg[ra + quad * 8]);
    qfA[1] = scale_q(*(const short8*)&qg[ra + 32 + quad * 8]);
    qfB[0] = scale_q(*(const short8*)&qg[rb + quad * 8]);
    qfB[1] = scale_q(*(const short8*)&qg[rb + 32 + quad * 8]);
  }

  floatx4 OA[4] = {}, OB[4] = {};
  float psA = 0.f, psB = 0.f;

  // staging map: threads 0..255 stage tile 2m, 256..511 stage tile 2m+1
  const int tsel = tid >> 8;
  const int t8 = tid & 255;
  const int str = t8 >> 2, sc = (t8 & 3) * 16;
  const int swr = (str & 7) << 3;        // write-side swizzle

  const int nktB = qtB + 1;
  const int M = (nktB + 1) >> 1;
  const int qrA = qtA * 64 + qs * 16 + l16;   // this lane's global q-row (A)
  const int qrB = qtB * 64 + qs * 16 + l16;

  const int sw = (l16 & 7) << 3;              // read-side swizzle
  const int rc0 = (quad * 8) ^ sw;
  const int rc1 = (32 + quad * 8) ^ sw;
  const int bpA = ((((lane >> 4) & 1) << 5) | l16) << 2;  // bpermute byte idx
  const int bpB = bpA + 64;

  // T14 prologue: issue loads for tile m=0 (kst = tsel, always < nktB >= 17)
  int4 kr0, kr1, vr0, vr1;
  {
    const size_t kro = (size_t)(tsel * 64 + str) * 2048 + sc;
    const size_t vro = (size_t)str * TT + tsel * 64 + sc;
    kr0 = *(const int4*)&kg[kro];
    kr1 = *(const int4*)&kg[kro + 8];
    vr0 = *(const int4*)&vtg[vro];
    vr1 = *(const int4*)&vtg[vro + 8];
  }

  for (int m = 0; m < M; ++m) {
    const int kt = 2 * m + par;    // this wave's key tile
    const int kt0 = kt * 64;
    __syncthreads();  // previous tiles consumed
    if (2 * m + tsel < nktB) {     // write-late: regs -> LDS (short)
      *(int4*)&Ks[tsel][str * 64 + (sc ^ swr)] = kr0;
      *(int4*)&Ks[tsel][str * 64 + ((sc + 8) ^ swr)] = kr1;
      *(int4*)&Vs[tsel][str * 64 + (sc ^ swr)] = vr0;
      *(int4*)&Vs[tsel][str * 64 + ((sc + 8) ^ swr)] = vr1;
    }
    __syncthreads();
    {
      // issue-early: loads for tile m+1, latency hides under compute below
      const int kst = 2 * (m + 1) + tsel;
      if (kst < nktB) {
        const size_t kro = (size_t)(kst * 64 + str) * 2048 + sc;
        const size_t vro = (size_t)str * TT + kst * 64 + sc;
        kr0 = *(const int4*)&kg[kro];
        kr1 = *(const int4*)&kg[kro + 8];
        vr0 = *(const int4*)&vtg[vro];
        vr1 = *(const int4*)&vtg[vro + 8];
      }
    }

    if (kt < nktB) {
      // ---- B tile ----
      floatx4 s[4];
      __builtin_amdgcn_s_setprio(1);
#pragma unroll
      for (int nt = 0; nt < 4; ++nt) {
        const int ro = (nt * 16 + l16) * 64;
        short8 k0 = *(const short8*)&Ks[par][ro + rc0];
        short8 k1 = *(const short8*)&Ks[par][ro + rc1];
        floatx4 zz = {0.f, 0.f, 0.f, 0.f};
        s[nt] = __builtin_amdgcn_mfma_f32_16x16x32_bf16(k0, qfB[0], zz, 0, 0, 0);
        s[nt] = __builtin_amdgcn_mfma_f32_16x16x32_bf16(k1, qfB[1], s[nt], 0, 0, 0);
      }
      __builtin_amdgcn_s_setprio(0);
      short8 pa0, pa1;
      {
        unsigned W[4][2];
        if (kt == qtB)
          exp_pack<true>(s, kt0, quad, qrB, psB, W);
        else
          exp_pack<false>(s, kt0, quad, qrB, psB, W);
        pfrag(W, bpA, bpB, quad, pa0, pa1);
      }
      __builtin_amdgcn_s_setprio(1);
#pragma unroll
      for (int nt = 0; nt < 4; ++nt) {
        const int ro = (nt * 16 + l16) * 64;
        short8 v0 = *(const short8*)&Vs[par][ro + rc0];
        short8 v1 = *(const short8*)&Vs[par][ro + rc1];
        OB[nt] = __builtin_amdgcn_mfma_f32_16x16x32_bf16(pa0, v0, OB[nt], 0, 0, 0);
        OB[nt] = __builtin_amdgcn_mfma_f32_16x16x32_bf16(pa1, v1, OB[nt], 0, 0, 0);
      }
      __builtin_amdgcn_s_setprio(0);

      // ---- A tile ----
      if (kt <= qtA) {
        __builtin_amdgcn_s_setprio(1);
#pragma unroll
        for (int nt = 0; nt < 4; ++nt) {
          const int ro = (nt * 16 + l16) * 64;
          short8 k0 = *(const short8*)&Ks[par][ro + rc0];
          short8 k1 = *(const short8*)&Ks[par][ro + rc1];
          floatx4 zz = {0.f, 0.f, 0.f, 0.f};
          s[nt] = __builtin_amdgcn_mfma_f32_16x16x32_bf16(k0, qfA[0], zz, 0, 0, 0);
          s[nt] = __builtin_amdgcn_mfma_f32_16x16x32_bf16(k1, qfA[1], s[nt], 0, 0, 0);
        }
        __builtin_amdgcn_s_setprio(0);
        {
          unsigned W[4][2];
          if (kt == qtA)
            exp_pack<true>(s, kt0, quad, qrA, psA, W);
          else
            exp_pack<false>(s, kt0, quad, qrA, psA, W);
          pfrag(W, bpA, bpB, quad, pa0, pa1);
        }
        __builtin_amdgcn_s_setprio(1);
#pragma unroll
        for (int nt = 0; nt < 4; ++nt) {
          const int ro = (nt * 16 + l16) * 64;
          short8 v0 = *(const short8*)&Vs[par][ro + rc0];
          short8 v1 = *(const short8*)&Vs[par][ro + rc1];
          OA[nt] = __builtin_amdgcn_mfma_f32_16x16x32_bf16(pa0, v0, OA[nt], 0, 0, 0);
          OA[nt] = __builtin_amdgcn_mfma_f32_16x16x32_bf16(pa1, v1, OA[nt], 0, 0, 0);
        }
        __builtin_amdgcn_s_setprio(0);
      }
    }
  }

  // ps is per-lane for q-row (qs*16 + l16); reduce over the 4 quads
  psA += __shfl_xor(psA, 16);
  psA += __shfl_xor(psA, 32);
  psB += __shfl_xor(psB, 16);
  psB += __shfl_xor(psB, 32);

  // cross-parity combine: O partials via red (overlay Ks, 16 KB = 4096 floats),
  // row-sums via lred (overlay Vs, 128 floats: [par][row])
  float* red = (float*)Ks;
  float* lred = (float*)Vs;

  __syncthreads();
  if (par == 1) {
#pragma unroll
    for (int nt = 0; nt < 4; ++nt)
#pragma unroll
      for (int r = 0; r < 4; ++r)
        red[(qs * 16 + quad * 4 + r) * 64 + nt * 16 + l16] = OA[nt][r];
  }
  if (quad == 0) lred[par * 64 + qs * 16 + l16] = psA;
  __syncthreads();
  if (par == 0) {
#pragma unroll
    for (int r = 0; r < 4; ++r) {
      int row = qs * 16 + quad * 4 + r;
      float rl = 1.0f / (lred[row] + lred[64 + row]);
      int qa = qtA * 64 + row;
#pragma unroll
      for (int nt = 0; nt < 4; ++nt) {
        float o = OA[nt][r] + red[row * 64 + nt * 16 + l16];
        z[(size_t)(b * TT + qa) * DD + h * 64 + nt * 16 + l16] = f2bf(o * rl);
      }
    }
  }
  __syncthreads();
  if (par == 1) {
#pragma unroll
    for (int nt = 0; nt < 4; ++nt)
#pragma unroll
      for (int r = 0; r < 4; ++r)
        red[(qs * 16 + quad * 4 + r) * 64 + nt * 16 + l16] = OB[nt][r];
  }
  if (quad == 0) lred[par * 64 + qs * 16 + l16] = psB;
  __syncthreads();
  if (par == 0) {
#pragma unroll
    for (int r = 0; r < 4; ++r) {
      int row = qs * 16 + quad * 4 + r;
      float rl = 1.0f / (lred[row] + lred[64 + row]);
      int qb = qtB * 64 + row;
#pragma unroll
      for (int nt = 0; nt < 4; ++nt) {
        float o = OB[nt][r] + red[row * 64 + nt * 16 + l16];
        z[(size_t)(b * TT + qb) * DD + h * 64 + nt * 16 + l16] = f2bf(o * rl);
      }
    }
  }
}

extern "C" void kernel_launch(void* const* d_in, const int* in_sizes, int n_in,
                              void* d_out, int out_size, void* d_ws, size_t ws_size,
                              hipStream_t stream) {
  const float* x  = (const float*)d_in[0];   // [2,2048,1024]
  const float* Wa = (const float*)d_in[1];   // [3072,1024]
  const float* Wo = (const float*)d_in[2];   // [1024,1024]
  float* out = (float*)d_out;                // [2,2048,1024] fp32

  // 48 MB workspace
  u16* xb  = (u16*)d_ws;                       // 4096*1024  (8 MB)
  u16* Wab = xb  + (size_t)4096 * 1024;        // 3072*1024  (6 MB)
  u16* Wob = Wab + (size_t)3072 * 1024;        // 1024*1024  (2 MB)
  u16* qk  = Wob + (size_t)1024 * 1024;        // 4096*2048  (16 MB) Q|K only
  u16* z   = qk  + (size_t)4096 * 2048;        // 4096*1024  (8 MB)
  u16* vt  = z   + (size_t)4096 * 1024;        // 2048*2048  (8 MB) V transposed

  cvt3_kernel<<<8192, 256, 0, stream>>>(x, Wa, Wo, xb, 1048576, 786432, 262144);

  // fused: Q,K -> qk (width 2048); V -> vt (transposed).
  // T1 L2-chunked 1D grid: each XCD gets a compact 8m x 12n rectangle.
  gemm_ep<2, 128><<<768, 256, 0, stream>>>(xb, Wab, qk, vt, 4096, 3072, 1024);

  // T1: 1D bh-major grid (512 blocks) -> same-head blocks co-locate per XCD
  attn_flash8<<<512, 512, 0, stream>>>(qk, vt, z);

  // out-GEMM: BK=64 dbuf specialization (R3 swizzle + R6 dbuf, 48KB LDS)
  gemm_out64<<<dim3(32, 16), 256, 0, stream>>>(z, Wob, out);
}

// Round 16
// 160.408 us; speedup vs baseline: 1.0274x; 1.0274x over previous
//
#include <hip/hip_runtime.h>
#include <cstddef>

typedef unsigned short u16;
typedef __attribute__((ext_vector_type(4))) float floatx4;
typedef __attribute__((ext_vector_type(8))) short short8;
typedef __attribute__((ext_vector_type(4))) unsigned int uintx4;

#define TT 2048
#define DD 1024
#define NH 16
#define ATT_SCALE (1.0f / 32.0f)

__device__ __forceinline__ u16 f2bf(float f) {
  unsigned u = __builtin_bit_cast(unsigned, f);
  u += 0x7fffu + ((u >> 16) & 1u);  // RNE
  return (u16)(u >> 16);
}

// pack two f32 -> (bf16,bf16) in one u32, a in low half (RNE)
__device__ __forceinline__ unsigned pack2(float a, float b) {
#if __has_builtin(__builtin_amdgcn_cvt_pk_bf16_f32)
  auto t = __builtin_amdgcn_cvt_pk_bf16_f32(a, b);
  return __builtin_bit_cast(unsigned, t);
#else
  unsigned ua = __builtin_bit_cast(unsigned, a);
  ua += 0x7fffu + ((ua >> 16) & 1u);
  unsigned ub = __builtin_bit_cast(unsigned, b);
  ub += 0x7fffu + ((ub >> 16) & 1u);
  return (ua >> 16) | (ub & 0xffff0000u);
#endif
}

// async global->LDS, 16B per lane (LDS dest wave-uniform base + lane*16)
__device__ __forceinline__ void g2l16(const u16* g, u16* l) {
#if __has_builtin(__builtin_amdgcn_global_load_lds)
  __builtin_amdgcn_global_load_lds(
      (const __attribute__((address_space(1))) unsigned int*)g,
      (__attribute__((address_space(3))) unsigned int*)l, 16, 0, 0);
#else
  *(int4*)l = *(const int4*)g;
#endif
}

// scale bf16x8 by 1/32 (exact: exponent shift)
__device__ __forceinline__ short8 scale_q(short8 q) {
  short8 r;
#pragma unroll
  for (int i = 0; i < 8; ++i) {
    float f = __builtin_bit_cast(float, ((unsigned)(u16)q[i]) << 16) * ATT_SCALE;
    r[i] = (short)f2bf(f);
  }
  return r;
}

// one kernel for all three fp32->bf16 conversions (outputs contiguous in ws)
__global__ __launch_bounds__(256) void cvt3_kernel(const float* __restrict__ a,
                                                   const float* __restrict__ b,
                                                   const float* __restrict__ c,
                                                   u16* __restrict__ out,
                                                   int na, int nb, int nc) {
  int i = blockIdx.x * 256 + threadIdx.x;
  const float* src;
  int j;
  if (i < na) { src = a; j = i; }
  else if (i < na + nb) { src = b; j = i - na; }
  else if (i < na + nb + nc) { src = c; j = i - na - nb; }
  else return;
  float4 v = ((const float4*)src)[j];
  ((ushort4*)out)[i] = make_ushort4(f2bf(v.x), f2bf(v.y), f2bf(v.z), f2bf(v.w));
}

// C[m,n] = sum_k A[m,k]*Bm[n,k]. 128xBN tile, double-buffered BK=32 chunks
// with plain __syncthreads. SESSION-MEASURED OPTIMUM for this template
// (R6/R7/R9/R10 triangulation; counted-vmcnt asm and 256^2 tiles both
// regress; R15 L2-chunked grid decode null). Epilogue via 32KB LDS
// scratch -> coalesced 16B stores.
// MODE 0: fp32 out (width N). MODE 1: bf16 out (width N).
// MODE 2 (qkv-fused): cols<2048 -> bf16 qk buffer (width 2048);
//                     cols>=2048 -> V written TRANSPOSED to vt.
template <int MODE, int BN>
__global__ __launch_bounds__(256) void gemm_ep(const u16* __restrict__ A,
                                               const u16* __restrict__ Bm,
                                               void* __restrict__ C,
                                               u16* __restrict__ vt,
                                               int M, int N, int K) {
  constexpr int NT = BN / 32;
  __shared__ __attribute__((aligned(16))) unsigned char shmem[32768];
  u16* As = (u16*)shmem;                 // [2][128*32]
  u16* Bs = As + 2 * 128 * 32;           // [2][BN*32]

  const int tid = threadIdx.x;
  const int lane = tid & 63;
  const int wave = tid >> 6;
  const int quad = lane >> 4;
  const int l16 = lane & 15;
  const int wm = (wave >> 1) * 64;
  const int wn = (wave & 1) * (BN / 2);
  const int m0 = blockIdx.x * 128;
  const int n0 = blockIdx.y * BN;

  const int srow = tid >> 2;        // 0..63 (row within a 64-row staging half)
  const int scol = (tid & 3) * 8;   // 8-u16 chunk within the 32-wide row
  const int sl = tid * 8;           // linear LDS dest (u16), lane*16B per wave

  floatx4 acc[4][NT] = {};

  auto stage = [&](int b, int k0) {
    g2l16(&A[(size_t)(m0 + srow) * K + k0 + scol], &As[b * 4096 + sl]);
    g2l16(&A[(size_t)(m0 + 64 + srow) * K + k0 + scol], &As[b * 4096 + 2048 + sl]);
    g2l16(&Bm[(size_t)(n0 + srow) * K + k0 + scol], &Bs[b * (BN * 32) + sl]);
    if (BN == 128)
      g2l16(&Bm[(size_t)(n0 + 64 + srow) * K + k0 + scol], &Bs[b * 4096 + 2048 + sl]);
  };
  auto compute = [&](int b) {
    short8 af[4];
#pragma unroll
    for (int mt = 0; mt < 4; ++mt)
      af[mt] = *(const short8*)&As[b * 4096 + (wm + mt * 16 + l16) * 32 + quad * 8];
#pragma unroll
    for (int nt = 0; nt < NT; ++nt) {
      short8 bf = *(const short8*)&Bs[b * (BN * 32) + (wn + nt * 16 + l16) * 32 + quad * 8];
#pragma unroll
      for (int mt = 0; mt < 4; ++mt)
        acc[mt][nt] = __builtin_amdgcn_mfma_f32_16x16x32_bf16(af[mt], bf, acc[mt][nt], 0, 0, 0);
    }
  };

  stage(0, 0);
  for (int k0 = 0; k0 < K; k0 += 64) {
    __syncthreads();                       // drains stage(buf0, chunk k0)
    if (k0 + 32 < K) stage(1, k0 + 32);    // flies under compute(0)
    compute(0);
    __syncthreads();                       // drains stage(buf1); compute(0) done
    if (k0 + 64 < K) stage(0, k0 + 64);    // flies under compute(1)
    compute(1);
  }

  __syncthreads();  // all staging reads done -> shmem becomes epilogue scratch

  if (MODE == 2 && n0 >= 2048) {
    // V region, transposed: scratch [n_local][t_local] u16 (128x128 = 32KB),
    // t XOR-swizzled by (n&7)<<3 (bits 3..5; preserves 4-u16 write alignment).
    u16* scr = (u16*)shmem;
    const int bidx = m0 >> 11;
    const int tb = m0 & 2047;
#pragma unroll
    for (int mt = 0; mt < 4; ++mt)
#pragma unroll
      for (int nt = 0; nt < NT; ++nt) {
        int nl = wn + nt * 16 + l16;
        int tl = wm + mt * 16 + quad * 4;
        int sz = (nl & 7) << 3;
        *(unsigned*)&scr[nl * 128 + (tl ^ sz)] = pack2(acc[mt][nt][0], acc[mt][nt][1]);
        *(unsigned*)&scr[nl * 128 + ((tl + 2) ^ sz)] = pack2(acc[mt][nt][2], acc[mt][nt][3]);
      }
    __syncthreads();
    // stream out: 8 passes x 16 n-rows x 256B contiguous along t
#pragma unroll
    for (int ps = 0; ps < 8; ++ps) {
      int nl = ps * 16 + (tid >> 4);
      int ck = (tid & 15) * 8;
      int sz = (nl & 7) << 3;
      int4 v = *(const int4*)&scr[nl * 128 + (ck ^ sz)];
      size_t vrow = (size_t)(bidx * 1024 + n0 + nl - 2048);
      *(int4*)&vt[vrow * TT + tb + ck] = v;
    }
  } else if (MODE >= 1) {
    // bf16 [m][BN] scratch, col XOR-swizzled by quad bits to de-alias banks
    const int cw = (MODE == 2) ? 2048 : N;
    constexpr int SH = (BN == 128) ? 5 : 4;
    u16* scr = (u16*)shmem;
#pragma unroll
    for (int mt = 0; mt < 4; ++mt)
#pragma unroll
      for (int nt = 0; nt < NT; ++nt)
#pragma unroll
        for (int r = 0; r < 4; ++r) {
          int ml = wm + mt * 16 + quad * 4 + r;
          int nl = wn + nt * 16 + l16;
          scr[ml * BN + (nl ^ (((ml >> 2) & 3) << SH))] = f2bf(acc[mt][nt][r]);
        }
    __syncthreads();
    constexpr int RPP = 2048 / BN;          // rows per pass (16 or 32)
    constexpr int CPT = BN / 8;             // col-chunks per row
#pragma unroll
    for (int ps = 0; ps < 128 / RPP; ++ps) {
      int ml = ps * RPP + tid / CPT;
      int ck = (tid % CPT) * 8;
      int sz = ((ml >> 2) & 3) << SH;
      int4 v = *(const int4*)&scr[ml * BN + (ck ^ sz)];
      *(int4*)&((u16*)C)[(size_t)(m0 + ml) * cw + n0 + ck] = v;
    }
  } else {
    // fp32 [m][64] scratch (32KB), col XOR-swizzled by quad bits
    float* scrf = (float*)shmem;
#pragma unroll
    for (int mt = 0; mt < 4; ++mt)
#pragma unroll
      for (int nt = 0; nt < NT; ++nt)
#pragma unroll
        for (int r = 0; r < 4; ++r) {
          int ml = wm + mt * 16 + quad * 4 + r;
          int nl = wn + nt * 16 + l16;
          scrf[ml * 64 + (nl ^ (((ml >> 2) & 3) << 4))] = acc[mt][nt][r];
        }
    __syncthreads();
#pragma unroll
    for (int ps = 0; ps < 8; ++ps) {
      int ml = ps * 16 + (tid >> 4);
      int ck = (tid & 15) * 4;
      int sz = ((ml >> 2) & 3) << 4;
      float4 v = *(const float4*)&scrf[ml * 64 + (ck ^ sz)];
      *(float4*)&((float*)C)[(size_t)(m0 + ml) * N + n0 + ck] = v;
    }
  }
}

// out-GEMM specialization: 128x64 tile, BK=64 chunks double-buffered.
// R3-verified T2 both-sides swizzle + R6 dbuf skeleton. R14: WIN (-2.6us).
// LDS 48KB. fp32 LDS-scratch epilogue.
__global__ __launch_bounds__(256) void gemm_out64(const u16* __restrict__ A,
                                                  const u16* __restrict__ Bm,
                                                  float* __restrict__ C) {
  constexpr int K = 1024;
  constexpr int N = 1024;
  __shared__ __attribute__((aligned(16))) unsigned char shmem[49152];
  u16* As = (u16*)shmem;                 // [2][128*64] = 32 KB
  u16* Bs = As + 2 * 128 * 64;           // [2][64*64]  = 16 KB

  const int tid = threadIdx.x;
  const int lane = tid & 63;
  const int wave = tid >> 6;
  const int quad = lane >> 4;
  const int l16 = lane & 15;
  const int wm = (wave >> 1) * 64;
  const int wn = (wave & 1) * 32;
  const int m0 = blockIdx.x * 128;
  const int n0 = blockIdx.y * 64;

  // staging: per gload op, 256 thr cover 32 rows x 64 cols (8-u16 chunks)
  const int srow = tid >> 3;                        // 0..31
  const int scol = ((tid & 7) ^ (srow & 7)) * 8;    // pre-swizzled source col
  const int sdst = tid * 8;                         // linear LDS (u16)
  const int sw8 = l16 & 7;                          // read-side swizzle

  floatx4 acc[4][2] = {};

  auto stage = [&](int b, int k0) {
#pragma unroll
    for (int o = 0; o < 4; ++o)
      g2l16(&A[(size_t)(m0 + o * 32 + srow) * K + k0 + scol],
            &As[b * 8192 + o * 2048 + sdst]);
#pragma unroll
    for (int o = 0; o < 2; ++o)
      g2l16(&Bm[(size_t)(n0 + o * 32 + srow) * K + k0 + scol],
            &Bs[b * 4096 + o * 2048 + sdst]);
  };
  auto compute = [&](int b) {
#pragma unroll
    for (int kk = 0; kk < 2; ++kk) {
      short8 af[4];
#pragma unroll
      for (int mt = 0; mt < 4; ++mt)
        af[mt] = *(const short8*)&As[b * 8192 + (wm + mt * 16 + l16) * 64 +
                                     (((kk << 2) | quad) ^ sw8) * 8];
#pragma unroll
      for (int nt = 0; nt < 2; ++nt) {
        short8 bf = *(const short8*)&Bs[b * 4096 + (wn + nt * 16 + l16) * 64 +
                                        (((kk << 2) | quad) ^ sw8) * 8];
#pragma unroll
        for (int mt = 0; mt < 4; ++mt)
          acc[mt][nt] = __builtin_amdgcn_mfma_f32_16x16x32_bf16(af[mt], bf, acc[mt][nt], 0, 0, 0);
      }
    }
  };

  stage(0, 0);
  for (int k0 = 0; k0 < K; k0 += 128) {
    __syncthreads();                        // stage(buf0, k0) landed
    stage(1, k0 + 64);                      // k0+64 <= 960 < K always
    compute(0);
    __syncthreads();                        // stage(buf1) landed; buf0 free
    if (k0 + 128 < K) stage(0, k0 + 128);
    compute(1);
  }

  __syncthreads();  // shmem becomes epilogue scratch
  // fp32 [m][64] scratch (32KB), col XOR-swizzled by quad bits
  float* scrf = (float*)shmem;
#pragma unroll
  for (int mt = 0; mt < 4; ++mt)
#pragma unroll
    for (int nt = 0; nt < 2; ++nt)
#pragma unroll
      for (int r = 0; r < 4; ++r) {
        int ml = wm + mt * 16 + quad * 4 + r;
        int nl = wn + nt * 16 + l16;
        scrf[ml * 64 + (nl ^ (((ml >> 2) & 3) << 4))] = acc[mt][nt][r];
      }
  __syncthreads();
#pragma unroll
  for (int ps = 0; ps < 8; ++ps) {
    int ml = ps * 16 + (tid >> 4);
    int ck = (tid & 15) * 4;
    int sz = ((ml >> 2) & 3) << 4;
    float4 v = *(const float4*)&scrf[ml * 64 + (ck ^ sz)];
    *(float4*)&C[(size_t)(m0 + ml) * N + n0 + ck] = v;
  }
}

// exp + causal-mask + pack to bf16 pairs, per nt-block. DIAG: apply mask.
template <bool DIAG>
__device__ __forceinline__ void exp_pack(const floatx4* s, int kt0, int quad,
                                         int qr, float& ps, unsigned W[4][2]) {
#pragma unroll
  for (int nt = 0; nt < 4; ++nt) {
    float e[4];
#pragma unroll
    for (int r = 0; r < 4; ++r) {
      float v = __expf(s[nt][r]);
      if (DIAG) {
        int kk = kt0 + nt * 16 + quad * 4 + r;
        v = (kk <= qr) ? v : 0.f;
      }
      ps += v;
      e[r] = v;
    }
    W[nt][0] = pack2(e[0], e[1]);
    W[nt][1] = pack2(e[2], e[3]);
  }
}

// Build the PV A-fragment in-register from swapped-QK^T output.
// Lane (quad,l16) holds P[q=l16][k=16nt+4quad+r] (packed in W[nt][c]).
// A-frag needs P[q=l16][k=quad*8+j]: word j2 of pa0 pulls W[quad>>1][j2&1]
// from src lane ((quad&1)*32 + (j2>>1)*16 + l16); pa1 uses W[2|3].
__device__ __forceinline__ void pfrag(const unsigned W[4][2], int bpA, int bpB,
                                      int quad, short8& pa0, short8& pa1) {
  uintx4 a, b;
#pragma unroll
  for (int c = 0; c < 2; ++c) {
    unsigned x0 = (unsigned)__builtin_amdgcn_ds_bpermute(bpA, (int)W[0][c]);
    unsigned x1 = (unsigned)__builtin_amdgcn_ds_bpermute(bpA, (int)W[1][c]);
    unsigned y0 = (unsigned)__builtin_amdgcn_ds_bpermute(bpB, (int)W[0][c]);
    unsigned y1 = (unsigned)__builtin_amdgcn_ds_bpermute(bpB, (int)W[1][c]);
    a[c]     = (quad < 2) ? x0 : x1;
    a[2 + c] = (quad < 2) ? y0 : y1;
    unsigned u0 = (unsigned)__builtin_amdgcn_ds_bpermute(bpA, (int)W[2][c]);
    unsigned u1 = (unsigned)__builtin_amdgcn_ds_bpermute(bpA, (int)W[3][c]);
    unsigned t0 = (unsigned)__builtin_amdgcn_ds_bpermute(bpB, (int)W[2][c]);
    unsigned t1 = (unsigned)__builtin_amdgcn_ds_bpermute(bpB, (int)W[3][c]);
    b[c]     = (quad < 2) ? u0 : u1;
    b[2 + c] = (quad < 2) ? t0 : t1;
  }
  pa0 = __builtin_bit_cast(short8, a);
  pa1 = __builtin_bit_cast(short8, b);
}

// Paired flash attention, 512 threads = 4 q-slices x 2 key-parities.
// Swapped QK^T (mfma(K,Q) -> S^T with q lane-local), softmax + P->bf16
// fully in-register (cvt_pk + ds_bpermute), no Ps LDS round-trip.
// Ks/Vs stride 64 + XOR swizzle col^((row&7)<<3) -> conflict-free ds_read_b128.
// 32 KB LDS. Unnormalized-exp key-associative parity accumulation.
// Pairing (qtA=p, qtB=31-p) keeps per-block work uniform AND lets A reuse B's
// staged K/V tiles -- all waves stay busy.
// T1 XCD CO-LOCATION (R12: FETCH 67->12.9 MB, dur -10%): 1D bh-major grid
// (id%8 == bh%8) pins same-head blocks to one XCD L2 (2MB K/V <= 4MB L2).
// SESSION LEDGER (structure optimum):
//   R2: un-paired 1-tile blocks            -> 1.8x WORSE (imbalance + reg choke)
//   R5: 32-row split tiles                 -> 1.4x WORSE (wave idling)
//   R10: merged A/B sharing K/V LDS reads  -> 3x WORSE (VGPR spill, 225MB scratch)
//   R4: T14 async-STAGE split              -> 53.2 -> 44.5 us (KEPT)
//   R12: T1 bh-major grid                  -> 48.2 -> 43.4 us (KEPT)
__global__ __launch_bounds__(512, 4) void attn_flash8(const u16* __restrict__ qk,
                                                      const u16* __restrict__ vt,
                                                      u16* __restrict__ z) {
  __shared__ u16 Ks[2][64 * 64];   // per key-parity tile: Ks[p][key][d], swizzled
  __shared__ u16 Vs[2][64 * 64];   // Vs[p][d][key], swizzled

  const int tid = threadIdx.x;
  const int lane = tid & 63;
  const int wave = tid >> 6;   // 0..7
  const int qs = wave & 3;     // q-slice (16 rows)
  const int par = wave >> 2;   // key parity
  const int quad = lane >> 4;
  const int l16 = lane & 15;

  // T1: bh-major 1D grid (id%8 == bh%8 -> same-head blocks share an XCD L2)
  const int p = blockIdx.x >> 5;      // 0..15
  const int bh = blockIdx.x & 31;     // 0..31
  const int qtA = p, qtB = 31 - p;
  const int b = bh >> 4, h = bh & 15;

  const size_t bbase = (size_t)b * TT * 2048;
  const u16* qg = qk + bbase + h * 64;
  const u16* kg = qk + bbase + 1024 + h * 64;
  const u16* vtg = vt + (size_t)bh * 64 * TT;

  short8 qfA[2], qfB[2];
  {
    const size_t ra = (size_t)(qtA * 64 + qs * 16 + l16) * 2048;
    const size_t rb = (size_t)(qtB * 64 + qs * 16 + l16) * 2048;
    qfA[0] = scale_q(*(const short8*)&qg[ra + quad * 8]);
    qfA[1] = scale_q(*(const short8*)&qg[ra + 32 + quad * 8]);
    qfB[0] = scale_q(*(const short8*)&qg[rb + quad * 8]);
    qfB[1] = scale_q(*(const short8*)&qg[rb + 32 + quad * 8]);
  }

  floatx4 OA[4] = {}, OB[4] = {};
  float psA = 0.f, psB = 0.f;

  // staging map: threads 0..255 stage tile 2m, 256..511 stage tile 2m+1
  const int tsel = tid >> 8;
  const int t8 = tid & 255;
  const int str = t8 >> 2, sc = (t8 & 3) * 16;
  const int swr = (str & 7) << 3;        // write-side swizzle

  const int nktB = qtB + 1;
  const int M = (nktB + 1) >> 1;
  const int qrA = qtA * 64 + qs * 16 + l16;   // this lane's global q-row (A)
  const int qrB = qtB * 64 + qs * 16 + l16;

  const int sw = (l16 & 7) << 3;              // read-side swizzle
  const int rc0 = (quad * 8) ^ sw;
  const int rc1 = (32 + quad * 8) ^ sw;
  const int bpA = ((((lane >> 4) & 1) << 5) | l16) << 2;  // bpermute byte idx
  const int bpB = bpA + 64;

  // T14 prologue: issue loads for tile m=0 (kst = tsel, always < nktB >= 17)
  int4 kr0, kr1, vr0, vr1;
  {
    const size_t kro = (size_t)(tsel * 64 + str) * 2048 + sc;
    const size_t vro = (size_t)str * TT + tsel * 64 + sc;
    kr0 = *(const int4*)&kg[kro];
    kr1 = *(const int4*)&kg[kro + 8];
    vr0 = *(const int4*)&vtg[vro];
    vr1 = *(const int4*)&vtg[vro + 8];
  }

  for (int m = 0; m < M; ++m) {
    const int kt = 2 * m + par;    // this wave's key tile
    const int kt0 = kt * 64;
    __syncthreads();  // previous tiles consumed
    if (2 * m + tsel < nktB) {     // write-late: regs -> LDS (short)
      *(int4*)&Ks[tsel][str * 64 + (sc ^ swr)] = kr0;
      *(int4*)&Ks[tsel][str * 64 + ((sc + 8) ^ swr)] = kr1;
      *(int4*)&Vs[tsel][str * 64 + (sc ^ swr)] = vr0;
      *(int4*)&Vs[tsel][str * 64 + ((sc + 8) ^ swr)] = vr1;
    }
    __syncthreads();
    {
      // issue-early: loads for tile m+1, latency hides under compute below
      const int kst = 2 * (m + 1) + tsel;
      if (kst < nktB) {
        const size_t kro = (size_t)(kst * 64 + str) * 2048 + sc;
        const size_t vro = (size_t)str * TT + kst * 64 + sc;
        kr0 = *(const int4*)&kg[kro];
        kr1 = *(const int4*)&kg[kro + 8];
        vr0 = *(const int4*)&vtg[vro];
        vr1 = *(const int4*)&vtg[vro + 8];
      }
    }

    if (kt < nktB) {
      // ---- B tile ----
      floatx4 s[4];
      __builtin_amdgcn_s_setprio(1);
#pragma unroll
      for (int nt = 0; nt < 4; ++nt) {
        const int ro = (nt * 16 + l16) * 64;
        short8 k0 = *(const short8*)&Ks[par][ro + rc0];
        short8 k1 = *(const short8*)&Ks[par][ro + rc1];
        floatx4 zz = {0.f, 0.f, 0.f, 0.f};
        s[nt] = __builtin_amdgcn_mfma_f32_16x16x32_bf16(k0, qfB[0], zz, 0, 0, 0);
        s[nt] = __builtin_amdgcn_mfma_f32_16x16x32_bf16(k1, qfB[1], s[nt], 0, 0, 0);
      }
      __builtin_amdgcn_s_setprio(0);
      short8 pa0, pa1;
      {
        unsigned W[4][2];
        if (kt == qtB)
          exp_pack<true>(s, kt0, quad, qrB, psB, W);
        else
          exp_pack<false>(s, kt0, quad, qrB, psB, W);
        pfrag(W, bpA, bpB, quad, pa0, pa1);
      }
      __builtin_amdgcn_s_setprio(1);
#pragma unroll
      for (int nt = 0; nt < 4; ++nt) {
        const int ro = (nt * 16 + l16) * 64;
        short8 v0 = *(const short8*)&Vs[par][ro + rc0];
        short8 v1 = *(const short8*)&Vs[par][ro + rc1];
        OB[nt] = __builtin_amdgcn_mfma_f32_16x16x32_bf16(pa0, v0, OB[nt], 0, 0, 0);
        OB[nt] = __builtin_amdgcn_mfma_f32_16x16x32_bf16(pa1, v1, OB[nt], 0, 0, 0);
      }
      __builtin_amdgcn_s_setprio(0);

      // ---- A tile ----
      if (kt <= qtA) {
        __builtin_amdgcn_s_setprio(1);
#pragma unroll
        for (int nt = 0; nt < 4; ++nt) {
          const int ro = (nt * 16 + l16) * 64;
          short8 k0 = *(const short8*)&Ks[par][ro + rc0];
          short8 k1 = *(const short8*)&Ks[par][ro + rc1];
          floatx4 zz = {0.f, 0.f, 0.f, 0.f};
          s[nt] = __builtin_amdgcn_mfma_f32_16x16x32_bf16(k0, qfA[0], zz, 0, 0, 0);
          s[nt] = __builtin_amdgcn_mfma_f32_16x16x32_bf16(k1, qfA[1], s[nt], 0, 0, 0);
        }
        __builtin_amdgcn_s_setprio(0);
        {
          unsigned W[4][2];
          if (kt == qtA)
            exp_pack<true>(s, kt0, quad, qrA, psA, W);
          else
            exp_pack<false>(s, kt0, quad, qrA, psA, W);
          pfrag(W, bpA, bpB, quad, pa0, pa1);
        }
        __builtin_amdgcn_s_setprio(1);
#pragma unroll
        for (int nt = 0; nt < 4; ++nt) {
          const int ro = (nt * 16 + l16) * 64;
          short8 v0 = *(const short8*)&Vs[par][ro + rc0];
          short8 v1 = *(const short8*)&Vs[par][ro + rc1];
          OA[nt] = __builtin_amdgcn_mfma_f32_16x16x32_bf16(pa0, v0, OA[nt], 0, 0, 0);
          OA[nt] = __builtin_amdgcn_mfma_f32_16x16x32_bf16(pa1, v1, OA[nt], 0, 0, 0);
        }
        __builtin_amdgcn_s_setprio(0);
      }
    }
  }

  // ps is per-lane for q-row (qs*16 + l16); reduce over the 4 quads
  psA += __shfl_xor(psA, 16);
  psA += __shfl_xor(psA, 32);
  psB += __shfl_xor(psB, 16);
  psB += __shfl_xor(psB, 32);

  // cross-parity combine: O partials via red (overlay Ks, 16 KB = 4096 floats),
  // row-sums via lred (overlay Vs, 128 floats: [par][row])
  float* red = (float*)Ks;
  float* lred = (float*)Vs;

  __syncthreads();
  if (par == 1) {
#pragma unroll
    for (int nt = 0; nt < 4; ++nt)
#pragma unroll
      for (int r = 0; r < 4; ++r)
        red[(qs * 16 + quad * 4 + r) * 64 + nt * 16 + l16] = OA[nt][r];
  }
  if (quad == 0) lred[par * 64 + qs * 16 + l16] = psA;
  __syncthreads();
  if (par == 0) {
#pragma unroll
    for (int r = 0; r < 4; ++r) {
      int row = qs * 16 + quad * 4 + r;
      float rl = 1.0f / (lred[row] + lred[64 + row]);
      int qa = qtA * 64 + row;
#pragma unroll
      for (int nt = 0; nt < 4; ++nt) {
        float o = OA[nt][r] + red[row * 64 + nt * 16 + l16];
        z[(size_t)(b * TT + qa) * DD + h * 64 + nt * 16 + l16] = f2bf(o * rl);
      }
    }
  }
  __syncthreads();
  if (par == 1) {
#pragma unroll
    for (int nt = 0; nt < 4; ++nt)
#pragma unroll
      for (int r = 0; r < 4; ++r)
        red[(qs * 16 + quad * 4 + r) * 64 + nt * 16 + l16] = OB[nt][r];
  }
  if (quad == 0) lred[par * 64 + qs * 16 + l16] = psB;
  __syncthreads();
  if (par == 0) {
#pragma unroll
    for (int r = 0; r < 4; ++r) {
      int row = qs * 16 + quad * 4 + r;
      float rl = 1.0f / (lred[row] + lred[64 + row]);
      int qb = qtB * 64 + row;
#pragma unroll
      for (int nt = 0; nt < 4; ++nt) {
        float o = OB[nt][r] + red[row * 64 + nt * 16 + l16];
        z[(size_t)(b * TT + qb) * DD + h * 64 + nt * 16 + l16] = f2bf(o * rl);
      }
    }
  }
}

extern "C" void kernel_launch(void* const* d_in, const int* in_sizes, int n_in,
                              void* d_out, int out_size, void* d_ws, size_t ws_size,
                              hipStream_t stream) {
  const float* x  = (const float*)d_in[0];   // [2,2048,1024]
  const float* Wa = (const float*)d_in[1];   // [3072,1024]
  const float* Wo = (const float*)d_in[2];   // [1024,1024]
  float* out = (float*)d_out;                // [2,2048,1024] fp32

  // 48 MB workspace
  u16* xb  = (u16*)d_ws;                       // 4096*1024  (8 MB)
  u16* Wab = xb  + (size_t)4096 * 1024;        // 3072*1024  (6 MB)
  u16* Wob = Wab + (size_t)3072 * 1024;        // 1024*1024  (2 MB)
  u16* qk  = Wob + (size_t)1024 * 1024;        // 4096*2048  (16 MB) Q|K only
  u16* z   = qk  + (size_t)4096 * 2048;        // 4096*1024  (8 MB)
  u16* vt  = z   + (size_t)4096 * 1024;        // 2048*2048  (8 MB) V transposed

  cvt3_kernel<<<8192, 256, 0, stream>>>(x, Wa, Wo, xb, 1048576, 786432, 262144);

  // fused: Q,K -> qk (width 2048); V -> vt (transposed)
  gemm_ep<2, 128><<<dim3(32, 24), 256, 0, stream>>>(xb, Wab, qk, vt, 4096, 3072, 1024);

  // T1: 1D bh-major grid (512 blocks) -> same-head blocks co-locate per XCD
  attn_flash8<<<512, 512, 0, stream>>>(qk, vt, z);

  // out-GEMM: BK=64 dbuf specialization (R3 swizzle + R6 dbuf, 48KB LDS)
  gemm_out64<<<dim3(32, 16), 256, 0, stream>>>(z, Wob, out);
}